// Round 11
// baseline (488.109 us; speedup 1.0000x reference)
//
#include <hip/hip_runtime.h>

#define GI   768
#define HID  150
#define HPAD 160
#define DDIM 20

typedef __attribute__((ext_vector_type(8))) short v8s;
typedef __attribute__((ext_vector_type(4))) float f32x4;
typedef __attribute__((ext_vector_type(16))) float f32x16;

#define MFMA(A, B, C)   __builtin_amdgcn_mfma_f32_32x32x16_bf16(A, B, C, 0, 0, 0)
#define MFMA16(A, B, C) __builtin_amdgcn_mfma_f32_16x16x32_bf16(A, B, C, 0, 0, 0)

// round-to-nearest-even bf16
__device__ __forceinline__ ushort bf16rn(float x) {
  unsigned u = __float_as_uint(x);
  return (ushort)((u + 0x7fffu + ((u >> 16) & 1u)) >> 16);
}
// truncation split (hot path): x ~= hi + lo, residual ~2^-16 rel
__device__ __forceinline__ void tsplit(float x, ushort& h, ushort& l) {
  unsigned u = __float_as_uint(x);
  h = (ushort)(u >> 16);
  float d = x - __uint_as_float(u & 0xffff0000u);
  l = (ushort)(__float_as_uint(d) >> 16);
}
__device__ __forceinline__ uint4 pack8(const ushort* v) {
  uint4 r;
  r.x = v[0] | ((unsigned)v[1] << 16); r.y = v[2] | ((unsigned)v[3] << 16);
  r.z = v[4] | ((unsigned)v[5] << 16); r.w = v[6] | ((unsigned)v[7] << 16);
  return r;
}
__device__ __forceinline__ v8s mk8(const ushort* v) {
  union { uint4 u; v8s s; } t;
  t.u = pack8(v);
  return t.s;
}

// ---------------- segment boundaries ------------------------------------------
__global__ void seg_kernel(const int* __restrict__ mI, int* __restrict__ segs,
                           int P, int S) {
  int m = blockIdx.x * 256 + threadIdx.x;
  if (m > S) return;
  int lo = 0, hi = P;
  while (lo < hi) { int mid = (lo + hi) >> 1; if (mI[mid] < m) lo = mid + 1; else hi = mid; }
  segs[m] = lo;
}

// ---------------- phi lookup tables: phiW[21][HPAD] f32 -----------------------
__global__ void phi_kernel(const float* __restrict__ de, const float* __restrict__ ge,
                           const float* __restrict__ se, const float* __restrict__ W1,
                           float* __restrict__ phiW) {
  int idx = blockIdx.x * 256 + threadIdx.x;
  if (idx >= 21 * HPAD) return;
  int row = idx / HPAD, h = idx % HPAD;
  float v = 0.f;
  if (h < HID) {
    const float* emb; int off;
    if (row < 10)      { emb = de + row * DDIM;        off = 0; }
    else if (row < 18) { emb = ge + (row - 10) * DDIM; off = DDIM; }
    else               { emb = se + (row - 18) * DDIM; off = 2 * DDIM; }
    for (int k = 0; k < DDIM; ++k) v += emb[k] * W1[(3 * GI + off + k) * HID + h];
  }
  phiW[row * HPAD + h] = v;
}

// ---------------- weight prep -------------------------------------------------
// WC[10][24][64][8]  (h1c, rn-bf16, 16x16x32 B-frag): col = ct*16+(l&15),
//     k = s*32+8*(l>>4)+j, value W1[(2*GI+k)*HID+col]
// W16[20][24][64][8] (pre3, rn-bf16): col = ct*16+(l&15) over [A|B] 320
// W2B[5][10][64][8]  (score3, hi/lo split, 32x32 A-frag): h2 = rt*32+(l&31)
#define NWC  (10 * 24 * 512)
#define NW16 (20 * 24 * 512)
#define NW2B (5 * 10 * 512)
__global__ void pad2_kernel(const float* __restrict__ W1, const float* __restrict__ W2,
                            const float* __restrict__ b1, const float* __restrict__ b2,
                            const float* __restrict__ W3,
                            ushort* __restrict__ WC, ushort* __restrict__ W16,
                            ushort* __restrict__ W2Bhi, ushort* __restrict__ W2Blo,
                            float* __restrict__ b1p, float2* __restrict__ b2w3) {
  int idx = blockIdx.x * 256 + threadIdx.x;
  if (idx < NWC) {
    int ct = idx / (24 * 512); int r1 = idx % (24 * 512);
    int s = r1 / 512; int r2 = r1 % 512;
    int l = r2 / 8, j = r2 % 8;
    int col = ct * 16 + (l & 15);
    int k = s * 32 + 8 * (l >> 4) + j;
    float x = (col < HID) ? W1[(size_t)(2 * GI + k) * HID + col] : 0.f;
    WC[idx] = bf16rn(x); return;
  }
  idx -= NWC;
  if (idx < NW16) {
    int ct = idx / (24 * 512); int r1 = idx % (24 * 512);
    int s = r1 / 512; int r2 = r1 % 512;
    int l = r2 / 8, j = r2 % 8;
    int col = ct * 16 + (l & 15);
    int k = s * 32 + 8 * (l >> 4) + j;
    int seg = col / HPAD, h = col % HPAD;
    float x = (h < HID) ? W1[(size_t)(seg * GI + k) * HID + h] : 0.f;
    W16[idx] = bf16rn(x); return;
  }
  idx -= NW16;
  if (idx < NW2B) {
    int rt = idx / (10 * 512); int r1 = idx % (10 * 512);
    int s = r1 / 512; int r2 = r1 % 512;
    int l = r2 / 8, j = r2 % 8;
    int h2 = rt * 32 + (l & 31);
    int k = s * 16 + 8 * (l >> 5) + j;
    float x = (k < HID && h2 < HID) ? W2[(size_t)k * HID + h2] : 0.f;
    ushort hh = bf16rn(x);
    float lo = x - __uint_as_float((unsigned)hh << 16);
    W2Bhi[idx] = hh; W2Blo[idx] = bf16rn(lo); return;
  }
  idx -= NW2B;
  if (idx < HPAD) { b1p[idx] = (idx < HID) ? b1[idx] : 0.f; return; }
  idx -= HPAD;
  if (idx < HPAD) {
    b2w3[idx] = make_float2((idx < HID) ? b2[idx] : 0.f, (idx < HID) ? W3[idx] : 0.f);
    return;
  }
}

// ---------------- pre3: pre[s][0:320] = g[s]@[W1a|W1b], 16x16 tiles, 1 wave ---
__global__ __launch_bounds__(64, 4) void pre3_kernel(
    const float* __restrict__ g, const ushort* __restrict__ W16,
    float* __restrict__ pre, int S) {
  const int lane = threadIdx.x;
  const int ct = blockIdx.x;            // 20 col-tiles over 320
  const int row0 = blockIdx.y * 16;
  int srow = row0 + (lane & 15); if (srow >= S) srow = S - 1;
  const float* gp = g + (size_t)srow * GI + 8 * (lane >> 4);
  const ushort* wp = W16 + ((size_t)ct * 24 * 64 + lane) * 8;

  f32x4 acc = {};
#pragma unroll 2
  for (int s = 0; s < 24; ++s) {
    const float4 a0 = *(const float4*)(gp + s * 32);
    const float4 a1 = *(const float4*)(gp + s * 32 + 4);
    const v8s bh = *(const v8s*)(wp + (size_t)s * 512);
    float xr[8] = {a0.x, a0.y, a0.z, a0.w, a1.x, a1.y, a1.z, a1.w};
    ushort hs[8], ls[8];
#pragma unroll
    for (int j = 0; j < 8; ++j) tsplit(xr[j], hs[j], ls[j]);
    const v8s ah = mk8(hs), al = mk8(ls);
    acc = MFMA16(ah, bh, acc);
    acc = MFMA16(al, bh, acc);
  }
  const int col = ct * 16 + (lane & 15);
#pragma unroll
  for (int r = 0; r < 4; ++r) {
    int sr = row0 + (lane >> 4) * 4 + r;
    if (sr < S) pre[(size_t)sr * 320 + col] = acc[r];
  }
}

// ---------------- h1c: per-pair h1 GEMM, 16 pairs/wave, 16x16x32, no LDS ------
// A: lane holds pair row (lane&15), k-octet (lane>>4); B: WC packed fragments.
// Grid = P/16 = 5000 waves -> ~5 waves/SIMD available (TLP fix).
__global__ __launch_bounds__(64, 4) void h1c_kernel(
    const float* __restrict__ g, const float* __restrict__ pre,
    const float* __restrict__ phiW, const ushort* __restrict__ WC,
    const float* __restrict__ b1p,
    const int* __restrict__ mI, const int* __restrict__ aI,
    const int* __restrict__ db, const int* __restrict__ ge, const int* __restrict__ sp,
    ushort* __restrict__ h1b, int P) {
  const int lane = threadIdx.x;
  const int lrow = lane & 15;          // pair-in-tile (A) / col-in-tile (C)
  const int kg = lane >> 4;            // k-octet group
  const int p0 = blockIdx.x * 16;

  const int myp = p0 + lrow;
  const int iA = mI[myp], jA = aI[myp];
  const int rdL = db[myp], rgL = 10 + ge[myp], rsL = 18 + sp[myp];

  const float* gi = g + (size_t)iA * GI + 8 * kg;
  const float* gj = g + (size_t)jA * GI + 8 * kg;

  f32x4 acc[10];
  {
    f32x4 z = {};
#pragma unroll
    for (int c = 0; c < 10; ++c) acc[c] = z;
  }

#pragma unroll 2
  for (int s = 0; s < 24; ++s) {
    const int d0 = s * 32;
    const float4 a0 = *(const float4*)(gi + d0);
    const float4 a1 = *(const float4*)(gi + d0 + 4);
    const float4 b0 = *(const float4*)(gj + d0);
    const float4 b1v = *(const float4*)(gj + d0 + 4);
    float xr[8] = {a0.x * b0.x, a0.y * b0.y, a0.z * b0.z, a0.w * b0.w,
                   a1.x * b1v.x, a1.y * b1v.y, a1.z * b1v.z, a1.w * b1v.w};
    ushort hs[8], ls[8];
#pragma unroll
    for (int j = 0; j < 8; ++j) tsplit(xr[j], hs[j], ls[j]);
    const v8s ah = mk8(hs), al = mk8(ls);
#pragma unroll
    for (int c = 0; c < 10; ++c) {
      const v8s w = *(const v8s*)(WC + ((size_t)(c * 24 + s) * 64 + lane) * 8);
      acc[c] = MFMA16(ah, w, acc[c]);
      acc[c] = MFMA16(al, w, acc[c]);
    }
  }

  // epilogue: C/D mapping col = lane&15, pair = (lane>>4)*4 + r
#pragma unroll
  for (int r = 0; r < 4; ++r) {
    const int p = kg * 4 + r;
    const int pI = __shfl(iA, p);
    const int pJ = __shfl(jA, p);
    const int rd = __shfl(rdL, p), rg = __shfl(rgL, p), rs = __shfl(rsL, p);
    const float* preI = pre + (size_t)pI * 320;
    const float* preJ = pre + (size_t)pJ * 320 + 160;
    const size_t prow = (size_t)(p0 + p) * 160;
#pragma unroll
    for (int c = 0; c < 10; ++c) {
      const int col = c * 16 + lrow;
      float v = acc[c][r] + b1p[col] + preI[col] + preJ[col]
              + phiW[rd * HPAD + col] + phiW[rg * HPAD + col] + phiW[rs * HPAD + col];
      v = fmaxf(v, 0.f);
      h1b[prow + col] = bf16rn(v);
    }
  }
}

// ---------------- score3: score = relu(h1@W2+b2)@W3 + b3, 1 wave/block -------
// A = W2 (hi/lo split), B = h1 rows (single bf16) per-lane. 2 MFMAs per tile.
__global__ __launch_bounds__(64, 3) void score3_kernel(
    const ushort* __restrict__ h1b,
    const ushort* __restrict__ W2Bhi, const ushort* __restrict__ W2Blo,
    const float2* __restrict__ b2w3, const float* __restrict__ b3,
    float* __restrict__ sOut, int P) {
  const int lane = threadIdx.x;
  const int lcol = lane & 31, half = lane >> 5;
  const int p0 = blockIdx.x * 32;

  const ushort* hb = h1b + (size_t)(p0 + lcol) * 160 + 8 * half;

  f32x16 acc[5];
  {
    f32x16 z = {};
#pragma unroll
    for (int r = 0; r < 5; ++r) acc[r] = z;
  }

#pragma unroll 2
  for (int s = 0; s < 10; ++s) {
    const v8s b = *(const v8s*)(hb + s * 16);
#pragma unroll
    for (int r = 0; r < 5; ++r) {
      const size_t o = ((size_t)(r * 10 + s) * 64 + lane) * 8;
      const v8s ah = *(const v8s*)(W2Bhi + o);
      const v8s al = *(const v8s*)(W2Blo + o);
      acc[r] = MFMA(ah, b, acc[r]);
      acc[r] = MFMA(al, b, acc[r]);
    }
  }

  float part = 0.f;
#pragma unroll
  for (int r = 0; r < 5; ++r) {
#pragma unroll
    for (int q = 0; q < 16; ++q) {
      const int h2 = r * 32 + (q & 3) + 8 * (q >> 2) + 4 * half;
      const float2 bw = b2w3[h2];
      part += fmaxf(acc[r][q] + bw.x, 0.f) * bw.y;
    }
  }
  part += __shfl_xor(part, 32);
  if (lane < 32) sOut[p0 + lane] = part + b3[0];
}

// ---------------- mid: segment softmax -> weighted -> gated g update ----------
// 256 thr: dg = t&63 owns 12 d-cols, pg = t>>6 takes pairs st+pg::4
__global__ void mid_kernel(const float* __restrict__ g, const float* __restrict__ s1,
                           const int* __restrict__ segs, const int* __restrict__ aI,
                           const float* __restrict__ Wf, const float* __restrict__ bf,
                           float* __restrict__ g2) {
  const int m = blockIdx.x;
  const int t = threadIdx.x;  // 256
  const int st = segs[m], en = segs[m + 1], n = en - st;
  if (n == 0) {
    for (int d = t; d < GI; d += 256) g2[m * GI + d] = g[m * GI + d];
    return;
  }
  __shared__ float red[256];
  __shared__ float wred[4][GI];
  float mx = -INFINITY;
  for (int p = st + t; p < en; p += 256) mx = fmaxf(mx, s1[p]);
  red[t] = mx; __syncthreads();
  for (int s = 128; s > 0; s >>= 1) { if (t < s) red[t] = fmaxf(red[t], red[t + s]); __syncthreads(); }
  mx = red[0]; __syncthreads();
  const int dg = t & 63, pg = t >> 6;
  float wv[12];
#pragma unroll
  for (int u = 0; u < 12; ++u) wv[u] = 0.f;
  float esum = 0.f;
  for (int p = st + pg; p < en; p += 4) {
    const float e = expf(s1[p] - mx);
    esum += e;
    const float* gj = g + (size_t)aI[p] * GI + dg;
#pragma unroll
    for (int u = 0; u < 12; ++u) wv[u] += e * gj[u * 64];
  }
  red[t] = (dg == 0) ? esum : 0.f; __syncthreads();
  for (int s = 128; s > 0; s >>= 1) { if (t < s) red[t] += red[t + s]; __syncthreads(); }
  const float denom = red[0]; __syncthreads();
#pragma unroll
  for (int u = 0; u < 12; ++u) wred[pg][dg + u * 64] = wv[u];
  __syncthreads();
  float part = 0.f;
  float wfin[3];
#pragma unroll
  for (int u = 0; u < 3; ++u) {
    const int d = t + u * 256;
    float wsv = (wred[0][d] + wred[1][d] + wred[2][d] + wred[3][d]) / denom;
    wfin[u] = wsv;
    part += g[(size_t)m * GI + d] * Wf[d] + wsv * Wf[GI + d];
  }
  red[t] = part; __syncthreads();
  for (int s = 128; s > 0; s >>= 1) { if (t < s) red[t] += red[t + s]; __syncthreads(); }
  const float f = 1.f / (1.f + expf(-(red[0] + bf[0])));
#pragma unroll
  for (int u = 0; u < 3; ++u) {
    const int d = t + u * 256;
    g2[(size_t)m * GI + d] = f * (float)m + (1.f - f) * wfin[u];
  }
}

// ---------------- coref_scores[p] = ms[i] + ms[j] + s2[p] ---------------------
__global__ void coref_kernel(const float* __restrict__ ms, const float* __restrict__ s2,
                             const int* __restrict__ mI, const int* __restrict__ aI,
                             float* __restrict__ out, int P) {
  int p = blockIdx.x * 256 + threadIdx.x;
  if (p >= P) return;
  out[p] = ms[mI[p]] + ms[aI[p]] + s2[p];
}

// ---------------- final segment softmax with epsilon --------------------------
__global__ void final_kernel(const float* __restrict__ c, const int* __restrict__ segs,
                             float* __restrict__ pairP, float* __restrict__ epsP) {
  const int m = blockIdx.x;
  const int t = threadIdx.x;  // 256
  const int st = segs[m], en = segs[m + 1], n = en - st;
  __shared__ float red[256];
  float mx = -INFINITY;
  for (int p = st + t; p < en; p += 256) mx = fmaxf(mx, c[p]);
  red[t] = mx; __syncthreads();
  for (int s = 128; s > 0; s >>= 1) { if (t < s) red[t] = fmaxf(red[t], red[t + s]); __syncthreads(); }
  mx = red[0]; __syncthreads();
  const float m2 = (n > 0) ? fmaxf(mx, 0.f) : 0.f;
  float sm = 0.f;
  for (int p = st + t; p < en; p += 256) sm += expf(c[p] - m2);
  red[t] = sm; __syncthreads();
  for (int s = 128; s > 0; s >>= 1) { if (t < s) red[t] += red[t + s]; __syncthreads(); }
  const float denom = red[0] + expf(-m2);
  for (int p = st + t; p < en; p += 256) pairP[p] = expf(c[p] - m2) / denom;
  if (t == 0) epsP[m] = expf(-m2) / denom;
}

extern "C" void kernel_launch(void* const* d_in, const int* in_sizes, int n_in,
                              void* d_out, int out_size, void* d_ws, size_t ws_size,
                              hipStream_t stream) {
  const float* g_i  = (const float*)d_in[0];
  const float* ms   = (const float*)d_in[1];
  const int*   mI   = (const int*)d_in[2];
  const int*   aI   = (const int*)d_in[3];
  const int*   db   = (const int*)d_in[4];
  const int*   ge   = (const int*)d_in[5];
  const int*   sp   = (const int*)d_in[6];
  const float* de   = (const float*)d_in[7];
  const float* gemb = (const float*)d_in[8];
  const float* semb = (const float*)d_in[9];
  const float* W1   = (const float*)d_in[10];
  const float* b1   = (const float*)d_in[11];
  const float* W2   = (const float*)d_in[12];
  const float* b2   = (const float*)d_in[13];
  const float* W3   = (const float*)d_in[14];
  const float* b3   = (const float*)d_in[15];
  const float* Wf   = (const float*)d_in[16];
  const float* bf   = (const float*)d_in[17];

  const int S = in_sizes[0] / GI;
  const int P = in_sizes[2];
  float* out = (float*)d_out;                 // [coref P | pairP P | epsP S]

  char* ws = (char*)d_ws;
  size_t off = 0;
  auto take = [&](size_t bytes) -> char* {
    char* p = ws + off;
    off = (off + bytes + 15) & ~(size_t)15;
    return p;
  };
  int*    segs  = (int*)   take((size_t)(S + 1) * 4);
  float*  phiW  = (float*) take((size_t)21 * HPAD * 4);
  float*  pre   = (float*) take((size_t)S * 320 * 4);
  float*  g2    = (float*) take((size_t)S * GI * 4);
  float*  s1    = (float*) take((size_t)P * 4);
  float*  s2    = (float*) take((size_t)P * 4);
  ushort* WC    = (ushort*)take((size_t)NWC * 2);
  ushort* W16   = (ushort*)take((size_t)NW16 * 2);
  ushort* W2Bhi = (ushort*)take((size_t)NW2B * 2);
  ushort* W2Blo = (ushort*)take((size_t)NW2B * 2);
  float*  b1p   = (float*) take((size_t)HPAD * 4);
  float2* b2w3  = (float2*)take((size_t)HPAD * 8);
  ushort* h1b   = (ushort*)take((size_t)P * 160 * 2);

  const int gridSeg = (S + 1 + 255) / 256;
  const int gridPhi = (21 * HPAD + 255) / 256;
  const int padTot  = NWC + NW16 + NW2B + 2 * HPAD;
  const int gridPad = (padTot + 255) / 256;
  const dim3 gridPre(20, (S + 15) / 16);
  const int gridH   = P / 16;          // 5000 single-wave blocks
  const int gridS3  = P / 32;
  const int gridCor = (P + 255) / 256;

  seg_kernel<<<gridSeg, 256, 0, stream>>>(mI, segs, P, S);
  phi_kernel<<<gridPhi, 256, 0, stream>>>(de, gemb, semb, W1, phiW);
  pad2_kernel<<<gridPad, 256, 0, stream>>>(W1, W2, b1, b2, W3, WC, W16,
                                           W2Bhi, W2Blo, b1p, b2w3);

  // iteration 1 (g = g_i)
  pre3_kernel<<<gridPre, 64, 0, stream>>>(g_i, W16, pre, S);
  h1c_kernel<<<gridH, 64, 0, stream>>>(g_i, pre, phiW, WC, b1p,
                                       mI, aI, db, ge, sp, h1b, P);
  score3_kernel<<<gridS3, 64, 0, stream>>>(h1b, W2Bhi, W2Blo, b2w3, b3, s1, P);
  mid_kernel<<<S, 256, 0, stream>>>(g_i, s1, segs, aI, Wf, bf, g2);

  // iteration 2 (g = g2)
  pre3_kernel<<<gridPre, 64, 0, stream>>>(g2, W16, pre, S);
  h1c_kernel<<<gridH, 64, 0, stream>>>(g2, pre, phiW, WC, b1p,
                                       mI, aI, db, ge, sp, h1b, P);
  score3_kernel<<<gridS3, 64, 0, stream>>>(h1b, W2Bhi, W2Blo, b2w3, b3, s2, P);

  // outputs
  coref_kernel<<<gridCor, 256, 0, stream>>>(ms, s2, mI, aI, out, P);
  final_kernel<<<S, 256, 0, stream>>>(out, segs, out + P, out + 2 * (size_t)P);
}

// Round 12
// 447.752 us; speedup vs baseline: 1.0901x; 1.0901x over previous
//
#include <hip/hip_runtime.h>

#define GI   768
#define HID  150
#define HPAD 160
#define DDIM 20

typedef __attribute__((ext_vector_type(8))) short v8s;
typedef __attribute__((ext_vector_type(4))) float f32x4;

#define MFMA16(A, B, C) __builtin_amdgcn_mfma_f32_16x16x32_bf16(A, B, C, 0, 0, 0)

// round-to-nearest-even bf16
__device__ __forceinline__ ushort bf16rn(float x) {
  unsigned u = __float_as_uint(x);
  return (ushort)((u + 0x7fffu + ((u >> 16) & 1u)) >> 16);
}
__device__ __forceinline__ float b2f(ushort u) {
  return __uint_as_float((unsigned)u << 16);
}
// truncation split (hot path): x ~= hi + lo, residual ~2^-16 rel
__device__ __forceinline__ void tsplit(float x, ushort& h, ushort& l) {
  unsigned u = __float_as_uint(x);
  h = (ushort)(u >> 16);
  float d = x - __uint_as_float(u & 0xffff0000u);
  l = (ushort)(__float_as_uint(d) >> 16);
}
__device__ __forceinline__ uint4 pack8(const ushort* v) {
  uint4 r;
  r.x = v[0] | ((unsigned)v[1] << 16); r.y = v[2] | ((unsigned)v[3] << 16);
  r.z = v[4] | ((unsigned)v[5] << 16); r.w = v[6] | ((unsigned)v[7] << 16);
  return r;
}
__device__ __forceinline__ v8s mk8(const ushort* v) {
  union { uint4 u; v8s s; } t;
  t.u = pack8(v);
  return t.s;
}

// ---------------- segment boundaries ------------------------------------------
__global__ void seg_kernel(const int* __restrict__ mI, int* __restrict__ segs,
                           int P, int S) {
  int m = blockIdx.x * 256 + threadIdx.x;
  if (m > S) return;
  int lo = 0, hi = P;
  while (lo < hi) { int mid = (lo + hi) >> 1; if (mI[mid] < m) lo = mid + 1; else hi = mid; }
  segs[m] = lo;
}

// ---------------- phi lookup tables: phiW[21][HPAD] f32 -----------------------
__global__ void phi_kernel(const float* __restrict__ de, const float* __restrict__ ge,
                           const float* __restrict__ se, const float* __restrict__ W1,
                           float* __restrict__ phiW) {
  int idx = blockIdx.x * 256 + threadIdx.x;
  if (idx >= 21 * HPAD) return;
  int row = idx / HPAD, h = idx % HPAD;
  float v = 0.f;
  if (h < HID) {
    const float* emb; int off;
    if (row < 10)      { emb = de + row * DDIM;        off = 0; }
    else if (row < 18) { emb = ge + (row - 10) * DDIM; off = DDIM; }
    else               { emb = se + (row - 18) * DDIM; off = 2 * DDIM; }
    for (int k = 0; k < DDIM; ++k) v += emb[k] * W1[(3 * GI + off + k) * HID + h];
  }
  phiW[row * HPAD + h] = v;
}

// ---------------- g -> bf16 copy ----------------------------------------------
__global__ void g2b_kernel(const float* __restrict__ g, ushort* __restrict__ gb, int n4) {
  int i = blockIdx.x * 256 + threadIdx.x;
  if (i >= n4) return;
  const float4 v = *(const float4*)(g + 4 * (size_t)i);
  ushort4 o;
  o.x = bf16rn(v.x); o.y = bf16rn(v.y); o.z = bf16rn(v.z); o.w = bf16rn(v.w);
  *(ushort4*)(gb + 4 * (size_t)i) = o;
}

// ---------------- weight prep -------------------------------------------------
// WC[10][24][64][8]  (h1 phase1, rn-bf16 B-frag 16x16x32): col = ct*16+(l&15),
//     k = s*32+8*(l>>4)+j, value W1[(2*GI+k)*HID+col]
// W16[20][24][64][8] (pre3, rn-bf16): col = ct*16+(l&15) over [A|B] 320
// W2C[10][5][64][8]  (h1 phase2, hi/lo, 16x16x32 B-frag): col = ct*16+(l&15),
//     k = s*32+8*(l>>4)+j, value W2[k][col]
#define NWC  (10 * 24 * 512)
#define NW16 (20 * 24 * 512)
#define NW2C (10 * 5 * 512)
__global__ void pad2_kernel(const float* __restrict__ W1, const float* __restrict__ W2,
                            const float* __restrict__ b1, const float* __restrict__ b2,
                            const float* __restrict__ W3,
                            ushort* __restrict__ WC, ushort* __restrict__ W16,
                            ushort* __restrict__ W2Chi, ushort* __restrict__ W2Clo,
                            float* __restrict__ b1p, float2* __restrict__ b2w3) {
  int idx = blockIdx.x * 256 + threadIdx.x;
  if (idx < NWC) {
    int ct = idx / (24 * 512); int r1 = idx % (24 * 512);
    int s = r1 / 512; int r2 = r1 % 512;
    int l = r2 / 8, j = r2 % 8;
    int col = ct * 16 + (l & 15);
    int k = s * 32 + 8 * (l >> 4) + j;
    float x = (col < HID) ? W1[(size_t)(2 * GI + k) * HID + col] : 0.f;
    WC[idx] = bf16rn(x); return;
  }
  idx -= NWC;
  if (idx < NW16) {
    int ct = idx / (24 * 512); int r1 = idx % (24 * 512);
    int s = r1 / 512; int r2 = r1 % 512;
    int l = r2 / 8, j = r2 % 8;
    int col = ct * 16 + (l & 15);
    int k = s * 32 + 8 * (l >> 4) + j;
    int seg = col / HPAD, h = col % HPAD;
    float x = (h < HID) ? W1[(size_t)(seg * GI + k) * HID + h] : 0.f;
    W16[idx] = bf16rn(x); return;
  }
  idx -= NW16;
  if (idx < NW2C) {
    int ct = idx / (5 * 512); int r1 = idx % (5 * 512);
    int s = r1 / 512; int r2 = r1 % 512;
    int l = r2 / 8, j = r2 % 8;
    int col = ct * 16 + (l & 15);
    int k = s * 32 + 8 * (l >> 4) + j;
    float x = (k < HID && col < HID) ? W2[(size_t)k * HID + col] : 0.f;
    ushort hh = bf16rn(x);
    float lo = x - __uint_as_float((unsigned)hh << 16);
    W2Chi[idx] = hh; W2Clo[idx] = bf16rn(lo); return;
  }
  idx -= NW2C;
  if (idx < HPAD) { b1p[idx] = (idx < HID) ? b1[idx] : 0.f; return; }
  idx -= HPAD;
  if (idx < HPAD) {
    b2w3[idx] = make_float2((idx < HID) ? b2[idx] : 0.f, (idx < HID) ? W3[idx] : 0.f);
    return;
  }
}

// ---------------- pre3: preb[s][0:320] = bf16(g[s]@[W1a|W1b]) -----------------
__global__ __launch_bounds__(64, 4) void pre3_kernel(
    const float* __restrict__ g, const ushort* __restrict__ W16,
    ushort* __restrict__ preb, int S) {
  const int lane = threadIdx.x;
  const int ct = blockIdx.x;            // 20 col-tiles over 320
  const int row0 = blockIdx.y * 16;
  int srow = row0 + (lane & 15); if (srow >= S) srow = S - 1;
  const float* gp = g + (size_t)srow * GI + 8 * (lane >> 4);
  const ushort* wp = W16 + ((size_t)ct * 24 * 64 + lane) * 8;

  f32x4 acc = {};
#pragma unroll 2
  for (int s = 0; s < 24; ++s) {
    const float4 a0 = *(const float4*)(gp + s * 32);
    const float4 a1 = *(const float4*)(gp + s * 32 + 4);
    const v8s bh = *(const v8s*)(wp + (size_t)s * 512);
    float xr[8] = {a0.x, a0.y, a0.z, a0.w, a1.x, a1.y, a1.z, a1.w};
    ushort hs[8], ls[8];
#pragma unroll
    for (int j = 0; j < 8; ++j) tsplit(xr[j], hs[j], ls[j]);
    const v8s ah = mk8(hs), al = mk8(ls);
    acc = MFMA16(ah, bh, acc);
    acc = MFMA16(al, bh, acc);
  }
  const int col = ct * 16 + (lane & 15);
#pragma unroll
  for (int r = 0; r < 4; ++r) {
    int sr = row0 + (lane >> 4) * 4 + r;
    if (sr < S) preb[(size_t)sr * 320 + col] = bf16rn(acc[r]);
  }
}

// ---------------- h1s: fused per-pair MLP, 16 pairs/wave, 1 wave, no barriers -
// phase1: h1 = relu((g_i.*g_j)@W1c + pre_i + pre_j + phi + b1) -> 5KB LDS
// phase2: score = relu(h1@W2 + b2) @ W3 + b3 -> sOut
// BF16G: gather g from bf16 copy (iter1); else f32 hi/lo (iter2).
template<bool BF16G>
__global__ __launch_bounds__(64, 4) void h1s_kernel(
    const float* __restrict__ g, const ushort* __restrict__ gb,
    const ushort* __restrict__ preb, const float* __restrict__ phiW,
    const ushort* __restrict__ WC,
    const ushort* __restrict__ W2Chi, const ushort* __restrict__ W2Clo,
    const float* __restrict__ b1p, const float2* __restrict__ b2w3,
    const float* __restrict__ b3,
    const int* __restrict__ mI, const int* __restrict__ aI,
    const int* __restrict__ db, const int* __restrict__ ge,
    const int* __restrict__ sp,
    float* __restrict__ sOut, int P) {
  __shared__ ushort h1L[16 * 160];
  const int lane = threadIdx.x;
  const int lrow = lane & 15, kg = lane >> 4;
  const int p0 = blockIdx.x * 16;
  const int myp = p0 + lrow;
  const int iA = mI[myp], jA = aI[myp];
  const int rdL = db[myp], rgL = 10 + ge[myp], rsL = 18 + sp[myp];

  f32x4 acc[10];
  {
    f32x4 z = {};
#pragma unroll
    for (int c = 0; c < 10; ++c) acc[c] = z;
  }

  if constexpr (BF16G) {
    // bf16 gather: 1 line/row/step, single-A MFMA (10/step)
    const ushort* gbi = gb + (size_t)iA * GI + 8 * kg;
    const ushort* gbj = gb + (size_t)jA * GI + 8 * kg;
#pragma unroll 2
    for (int s = 0; s < 24; ++s) {
      const int d0 = s * 32;
      const v8s ai = *(const v8s*)(gbi + d0);
      const v8s aj = *(const v8s*)(gbj + d0);
      ushort pr[8];
#pragma unroll
      for (int j = 0; j < 8; ++j)
        pr[j] = bf16rn(b2f((ushort)ai[j]) * b2f((ushort)aj[j]));
      const v8s ap = mk8(pr);
#pragma unroll
      for (int c = 0; c < 10; ++c) {
        const v8s w = *(const v8s*)(WC + ((size_t)(c * 24 + s) * 64 + lane) * 8);
        acc[c] = MFMA16(ap, w, acc[c]);
      }
    }
  } else {
    // f32 gather + hi/lo split A (20 MFMA/step) — r11 proven body
    const float* gi = g + (size_t)iA * GI + 8 * kg;
    const float* gj = g + (size_t)jA * GI + 8 * kg;
#pragma unroll 2
    for (int s = 0; s < 24; ++s) {
      const int d0 = s * 32;
      const float4 a0 = *(const float4*)(gi + d0);
      const float4 a1 = *(const float4*)(gi + d0 + 4);
      const float4 b0 = *(const float4*)(gj + d0);
      const float4 b1v = *(const float4*)(gj + d0 + 4);
      float xr[8] = {a0.x * b0.x, a0.y * b0.y, a0.z * b0.z, a0.w * b0.w,
                     a1.x * b1v.x, a1.y * b1v.y, a1.z * b1v.z, a1.w * b1v.w};
      ushort hs[8], ls[8];
#pragma unroll
      for (int j = 0; j < 8; ++j) tsplit(xr[j], hs[j], ls[j]);
      const v8s ah = mk8(hs), al = mk8(ls);
#pragma unroll
      for (int c = 0; c < 10; ++c) {
        const v8s w = *(const v8s*)(WC + ((size_t)(c * 24 + s) * 64 + lane) * 8);
        acc[c] = MFMA16(ah, w, acc[c]);
        acc[c] = MFMA16(al, w, acc[c]);
      }
    }
  }

  // ---- epilogue 1: + pre_i + pre_j + phi + b1, relu, bf16 -> LDS ----
#pragma unroll
  for (int r = 0; r < 4; ++r) {
    const int p = kg * 4 + r;
    const int pI = __shfl(iA, p);
    const int pJ = __shfl(jA, p);
    const int rd = __shfl(rdL, p), rg = __shfl(rgL, p), rs = __shfl(rsL, p);
    const ushort* prI = preb + (size_t)pI * 320;
    const ushort* prJ = preb + (size_t)pJ * 320 + 160;
#pragma unroll
    for (int c = 0; c < 10; ++c) {
      const int col = c * 16 + lrow;
      float v = acc[c][r] + b1p[col] + b2f(prI[col]) + b2f(prJ[col])
              + phiW[rd * HPAD + col] + phiW[rg * HPAD + col] + phiW[rs * HPAD + col];
      v = fmaxf(v, 0.f);
      h1L[p * 160 + col] = bf16rn(v);
    }
  }
  __syncthreads();   // single wave: near-free, orders LDS transpose

  // ---- phase 2: h2 = relu(h1 @ W2 + b2); score = h2 @ W3 + b3 ----
  f32x4 acc2[10];
  {
    f32x4 z = {};
#pragma unroll
    for (int ct = 0; ct < 10; ++ct) acc2[ct] = z;
  }
#pragma unroll
  for (int s = 0; s < 5; ++s) {
    const v8s a = *(const v8s*)(&h1L[lrow * 160 + s * 32 + 8 * kg]);
#pragma unroll
    for (int ct = 0; ct < 10; ++ct) {
      const size_t o = ((size_t)(ct * 5 + s) * 64 + lane) * 8;
      const v8s wh = *(const v8s*)(W2Chi + o);
      const v8s wl = *(const v8s*)(W2Clo + o);
      acc2[ct] = MFMA16(a, wh, acc2[ct]);
      acc2[ct] = MFMA16(a, wl, acc2[ct]);
    }
  }
  float part[4] = {0.f, 0.f, 0.f, 0.f};
#pragma unroll
  for (int ct = 0; ct < 10; ++ct) {
    const float2 bw = b2w3[ct * 16 + lrow];
#pragma unroll
    for (int r = 0; r < 4; ++r)
      part[r] += fmaxf(acc2[ct][r] + bw.x, 0.f) * bw.y;
  }
#pragma unroll
  for (int m = 1; m < 16; m <<= 1) {
#pragma unroll
    for (int r = 0; r < 4; ++r) part[r] += __shfl_xor(part[r], m, 16);
  }
  if (lrow == 0) {
    const float bb = b3[0];
#pragma unroll
    for (int r = 0; r < 4; ++r) sOut[p0 + kg * 4 + r] = part[r] + bb;
  }
}

// ---------------- mid: segment softmax -> weighted -> gated g update ----------
// j-gathers from bf16 copy gb; gate dot uses f32 g (coalesced).
__global__ void mid_kernel(const float* __restrict__ g, const ushort* __restrict__ gb,
                           const float* __restrict__ s1,
                           const int* __restrict__ segs, const int* __restrict__ aI,
                           const float* __restrict__ Wf, const float* __restrict__ bf,
                           float* __restrict__ g2) {
  const int m = blockIdx.x;
  const int t = threadIdx.x;  // 256
  const int st = segs[m], en = segs[m + 1], n = en - st;
  if (n == 0) {
    for (int d = t; d < GI; d += 256) g2[m * GI + d] = g[m * GI + d];
    return;
  }
  __shared__ float red[256];
  __shared__ float wred[4][GI];
  float mx = -INFINITY;
  for (int p = st + t; p < en; p += 256) mx = fmaxf(mx, s1[p]);
  red[t] = mx; __syncthreads();
  for (int s = 128; s > 0; s >>= 1) { if (t < s) red[t] = fmaxf(red[t], red[t + s]); __syncthreads(); }
  mx = red[0]; __syncthreads();
  const int dg = t & 63, pg = t >> 6;
  float wv[12];
#pragma unroll
  for (int u = 0; u < 12; ++u) wv[u] = 0.f;
  float esum = 0.f;
  for (int p = st + pg; p < en; p += 4) {
    const float e = expf(s1[p] - mx);
    esum += e;
    const ushort* gj = gb + (size_t)aI[p] * GI + dg;
#pragma unroll
    for (int u = 0; u < 12; ++u) wv[u] += e * b2f(gj[u * 64]);
  }
  red[t] = (dg == 0) ? esum : 0.f; __syncthreads();
  for (int s = 128; s > 0; s >>= 1) { if (t < s) red[t] += red[t + s]; __syncthreads(); }
  const float denom = red[0]; __syncthreads();
#pragma unroll
  for (int u = 0; u < 12; ++u) wred[pg][dg + u * 64] = wv[u];
  __syncthreads();
  float part = 0.f;
  float wfin[3];
#pragma unroll
  for (int u = 0; u < 3; ++u) {
    const int d = t + u * 256;
    float wsv = (wred[0][d] + wred[1][d] + wred[2][d] + wred[3][d]) / denom;
    wfin[u] = wsv;
    part += g[(size_t)m * GI + d] * Wf[d] + wsv * Wf[GI + d];
  }
  red[t] = part; __syncthreads();
  for (int s = 128; s > 0; s >>= 1) { if (t < s) red[t] += red[t + s]; __syncthreads(); }
  const float f = 1.f / (1.f + expf(-(red[0] + bf[0])));
#pragma unroll
  for (int u = 0; u < 3; ++u) {
    const int d = t + u * 256;
    g2[(size_t)m * GI + d] = f * (float)m + (1.f - f) * wfin[u];
  }
}

// ---------------- coref_scores[p] = ms[i] + ms[j] + s2[p] ---------------------
__global__ void coref_kernel(const float* __restrict__ ms, const float* __restrict__ s2,
                             const int* __restrict__ mI, const int* __restrict__ aI,
                             float* __restrict__ out, int P) {
  int p = blockIdx.x * 256 + threadIdx.x;
  if (p >= P) return;
  out[p] = ms[mI[p]] + ms[aI[p]] + s2[p];
}

// ---------------- final segment softmax with epsilon --------------------------
__global__ void final_kernel(const float* __restrict__ c, const int* __restrict__ segs,
                             float* __restrict__ pairP, float* __restrict__ epsP) {
  const int m = blockIdx.x;
  const int t = threadIdx.x;  // 256
  const int st = segs[m], en = segs[m + 1], n = en - st;
  __shared__ float red[256];
  float mx = -INFINITY;
  for (int p = st + t; p < en; p += 256) mx = fmaxf(mx, c[p]);
  red[t] = mx; __syncthreads();
  for (int s = 128; s > 0; s >>= 1) { if (t < s) red[t] = fmaxf(red[t], red[t + s]); __syncthreads(); }
  mx = red[0]; __syncthreads();
  const float m2 = (n > 0) ? fmaxf(mx, 0.f) : 0.f;
  float sm = 0.f;
  for (int p = st + t; p < en; p += 256) sm += expf(c[p] - m2);
  red[t] = sm; __syncthreads();
  for (int s = 128; s > 0; s >>= 1) { if (t < s) red[t] += red[t + s]; __syncthreads(); }
  const float denom = red[0] + expf(-m2);
  for (int p = st + t; p < en; p += 256) pairP[p] = expf(c[p] - m2) / denom;
  if (t == 0) epsP[m] = expf(-m2) / denom;
}

extern "C" void kernel_launch(void* const* d_in, const int* in_sizes, int n_in,
                              void* d_out, int out_size, void* d_ws, size_t ws_size,
                              hipStream_t stream) {
  const float* g_i  = (const float*)d_in[0];
  const float* ms   = (const float*)d_in[1];
  const int*   mI   = (const int*)d_in[2];
  const int*   aI   = (const int*)d_in[3];
  const int*   db   = (const int*)d_in[4];
  const int*   ge   = (const int*)d_in[5];
  const int*   sp   = (const int*)d_in[6];
  const float* de   = (const float*)d_in[7];
  const float* gemb = (const float*)d_in[8];
  const float* semb = (const float*)d_in[9];
  const float* W1   = (const float*)d_in[10];
  const float* b1   = (const float*)d_in[11];
  const float* W2   = (const float*)d_in[12];
  const float* b2   = (const float*)d_in[13];
  const float* W3   = (const float*)d_in[14];
  const float* b3   = (const float*)d_in[15];
  const float* Wf   = (const float*)d_in[16];
  const float* bf   = (const float*)d_in[17];

  const int S = in_sizes[0] / GI;
  const int P = in_sizes[2];
  float* out = (float*)d_out;                 // [coref P | pairP P | epsP S]

  char* ws = (char*)d_ws;
  size_t off = 0;
  auto take = [&](size_t bytes) -> char* {
    char* p = ws + off;
    off = (off + bytes + 15) & ~(size_t)15;
    return p;
  };
  int*    segs  = (int*)   take((size_t)(S + 1) * 4);
  float*  phiW  = (float*) take((size_t)21 * HPAD * 4);
  ushort* preb  = (ushort*)take((size_t)S * 320 * 2);
  float*  g2    = (float*) take((size_t)S * GI * 4);
  float*  s1    = (float*) take((size_t)P * 4);
  float*  s2    = (float*) take((size_t)P * 4);
  ushort* Gb    = (ushort*)take((size_t)S * GI * 2);
  ushort* WC    = (ushort*)take((size_t)NWC * 2);
  ushort* W16   = (ushort*)take((size_t)NW16 * 2);
  ushort* W2Chi = (ushort*)take((size_t)NW2C * 2);
  ushort* W2Clo = (ushort*)take((size_t)NW2C * 2);
  float*  b1p   = (float*) take((size_t)HPAD * 4);
  float2* b2w3  = (float2*)take((size_t)HPAD * 8);

  const int gridSeg = (S + 1 + 255) / 256;
  const int gridPhi = (21 * HPAD + 255) / 256;
  const int padTot  = NWC + NW16 + NW2C + 2 * HPAD;
  const int gridPad = (padTot + 255) / 256;
  const int n4      = S * GI / 4;
  const int gridGb  = (n4 + 255) / 256;
  const dim3 gridPre(20, (S + 15) / 16);
  const int gridH   = P / 16;          // 5000 single-wave blocks
  const int gridCor = (P + 255) / 256;

  seg_kernel<<<gridSeg, 256, 0, stream>>>(mI, segs, P, S);
  phi_kernel<<<gridPhi, 256, 0, stream>>>(de, gemb, semb, W1, phiW);
  pad2_kernel<<<gridPad, 256, 0, stream>>>(W1, W2, b1, b2, W3, WC, W16,
                                           W2Chi, W2Clo, b1p, b2w3);
  g2b_kernel<<<gridGb, 256, 0, stream>>>(g_i, Gb, n4);

  // iteration 1 (g = g_i; bf16 gathers)
  pre3_kernel<<<gridPre, 64, 0, stream>>>(g_i, W16, preb, S);
  h1s_kernel<true><<<gridH, 64, 0, stream>>>(g_i, Gb, preb, phiW, WC, W2Chi, W2Clo,
                                             b1p, b2w3, b3, mI, aI, db, ge, sp, s1, P);
  mid_kernel<<<S, 256, 0, stream>>>(g_i, Gb, s1, segs, aI, Wf, bf, g2);

  // iteration 2 (g = g2; f32 hi/lo gathers)
  pre3_kernel<<<gridPre, 64, 0, stream>>>(g2, W16, preb, S);
  h1s_kernel<false><<<gridH, 64, 0, stream>>>(g2, Gb, preb, phiW, WC, W2Chi, W2Clo,
                                              b1p, b2w3, b3, mI, aI, db, ge, sp, s2, P);

  // outputs
  coref_kernel<<<gridCor, 256, 0, stream>>>(ms, s2, mI, aI, out, P);
  final_kernel<<<S, 256, 0, stream>>>(out, segs, out + P, out + 2 * (size_t)P);
}

// Round 13
// 445.253 us; speedup vs baseline: 1.0963x; 1.0056x over previous
//
#include <hip/hip_runtime.h>

#define GI   768
#define HID  150
#define HPAD 160
#define DDIM 20

typedef __attribute__((ext_vector_type(8))) short v8s;
typedef __attribute__((ext_vector_type(4))) float f32x4;

#define MFMA16(A, B, C) __builtin_amdgcn_mfma_f32_16x16x32_bf16(A, B, C, 0, 0, 0)

// round-to-nearest-even bf16
__device__ __forceinline__ ushort bf16rn(float x) {
  unsigned u = __float_as_uint(x);
  return (ushort)((u + 0x7fffu + ((u >> 16) & 1u)) >> 16);
}
__device__ __forceinline__ float b2f(ushort u) {
  return __uint_as_float((unsigned)u << 16);
}
// truncation split (hot path): x ~= hi + lo, residual ~2^-16 rel
__device__ __forceinline__ void tsplit(float x, ushort& h, ushort& l) {
  unsigned u = __float_as_uint(x);
  h = (ushort)(u >> 16);
  float d = x - __uint_as_float(u & 0xffff0000u);
  l = (ushort)(__float_as_uint(d) >> 16);
}
__device__ __forceinline__ uint4 pack8(const ushort* v) {
  uint4 r;
  r.x = v[0] | ((unsigned)v[1] << 16); r.y = v[2] | ((unsigned)v[3] << 16);
  r.z = v[4] | ((unsigned)v[5] << 16); r.w = v[6] | ((unsigned)v[7] << 16);
  return r;
}
__device__ __forceinline__ v8s mk8(const ushort* v) {
  union { uint4 u; v8s s; } t;
  t.u = pack8(v);
  return t.s;
}

// ---------------- segment boundaries ------------------------------------------
__global__ void seg_kernel(const int* __restrict__ mI, int* __restrict__ segs,
                           int P, int S) {
  int m = blockIdx.x * 256 + threadIdx.x;
  if (m > S) return;
  int lo = 0, hi = P;
  while (lo < hi) { int mid = (lo + hi) >> 1; if (mI[mid] < m) lo = mid + 1; else hi = mid; }
  segs[m] = lo;
}

// ---------------- phi lookup tables: phiW[21][HPAD] f32 -----------------------
__global__ void phi_kernel(const float* __restrict__ de, const float* __restrict__ ge,
                           const float* __restrict__ se, const float* __restrict__ W1,
                           float* __restrict__ phiW) {
  int idx = blockIdx.x * 256 + threadIdx.x;
  if (idx >= 21 * HPAD) return;
  int row = idx / HPAD, h = idx % HPAD;
  float v = 0.f;
  if (h < HID) {
    const float* emb; int off;
    if (row < 10)      { emb = de + row * DDIM;        off = 0; }
    else if (row < 18) { emb = ge + (row - 10) * DDIM; off = DDIM; }
    else               { emb = se + (row - 18) * DDIM; off = 2 * DDIM; }
    for (int k = 0; k < DDIM; ++k) v += emb[k] * W1[(3 * GI + off + k) * HID + h];
  }
  phiW[row * HPAD + h] = v;
}

// ---------------- g -> bf16 copy ----------------------------------------------
__global__ void g2b_kernel(const float* __restrict__ g, ushort* __restrict__ gb, int n4) {
  int i = blockIdx.x * 256 + threadIdx.x;
  if (i >= n4) return;
  const float4 v = *(const float4*)(g + 4 * (size_t)i);
  ushort4 o;
  o.x = bf16rn(v.x); o.y = bf16rn(v.y); o.z = bf16rn(v.z); o.w = bf16rn(v.w);
  *(ushort4*)(gb + 4 * (size_t)i) = o;
}

// ---------------- weight prep -------------------------------------------------
// WC[10][24][64][8]  (h1 phase1, rn-bf16 B-frag 16x16x32): col = ct*16+(l&15),
//     k = s*32+8*(l>>4)+j, value W1[(2*GI+k)*HID+col]
// W16[20][24][64][8] (pre3, rn-bf16): col = ct*16+(l&15) over [A|B] 320
// W2C[10][5][64][8]  (h1 phase2, hi/lo, 16x16x32 B-frag): col = ct*16+(l&15),
//     k = s*32+8*(l>>4)+j, value W2[k][col]
#define NWC  (10 * 24 * 512)
#define NW16 (20 * 24 * 512)
#define NW2C (10 * 5 * 512)
__global__ void pad2_kernel(const float* __restrict__ W1, const float* __restrict__ W2,
                            const float* __restrict__ b1, const float* __restrict__ b2,
                            const float* __restrict__ W3,
                            ushort* __restrict__ WC, ushort* __restrict__ W16,
                            ushort* __restrict__ W2Chi, ushort* __restrict__ W2Clo,
                            float* __restrict__ b1p, float2* __restrict__ b2w3) {
  int idx = blockIdx.x * 256 + threadIdx.x;
  if (idx < NWC) {
    int ct = idx / (24 * 512); int r1 = idx % (24 * 512);
    int s = r1 / 512; int r2 = r1 % 512;
    int l = r2 / 8, j = r2 % 8;
    int col = ct * 16 + (l & 15);
    int k = s * 32 + 8 * (l >> 4) + j;
    float x = (col < HID) ? W1[(size_t)(2 * GI + k) * HID + col] : 0.f;
    WC[idx] = bf16rn(x); return;
  }
  idx -= NWC;
  if (idx < NW16) {
    int ct = idx / (24 * 512); int r1 = idx % (24 * 512);
    int s = r1 / 512; int r2 = r1 % 512;
    int l = r2 / 8, j = r2 % 8;
    int col = ct * 16 + (l & 15);
    int k = s * 32 + 8 * (l >> 4) + j;
    int seg = col / HPAD, h = col % HPAD;
    float x = (h < HID) ? W1[(size_t)(seg * GI + k) * HID + h] : 0.f;
    W16[idx] = bf16rn(x); return;
  }
  idx -= NW16;
  if (idx < NW2C) {
    int ct = idx / (5 * 512); int r1 = idx % (5 * 512);
    int s = r1 / 512; int r2 = r1 % 512;
    int l = r2 / 8, j = r2 % 8;
    int col = ct * 16 + (l & 15);
    int k = s * 32 + 8 * (l >> 4) + j;
    float x = (k < HID && col < HID) ? W2[(size_t)k * HID + col] : 0.f;
    ushort hh = bf16rn(x);
    float lo = x - __uint_as_float((unsigned)hh << 16);
    W2Chi[idx] = hh; W2Clo[idx] = bf16rn(lo); return;
  }
  idx -= NW2C;
  if (idx < HPAD) { b1p[idx] = (idx < HID) ? b1[idx] : 0.f; return; }
  idx -= HPAD;
  if (idx < HPAD) {
    b2w3[idx] = make_float2((idx < HID) ? b2[idx] : 0.f, (idx < HID) ? W3[idx] : 0.f);
    return;
  }
}

// ---------------- pre3: preb[s][0:320] = bf16(g[s]@[W1a|W1b]) -----------------
__global__ __launch_bounds__(64, 4) void pre3_kernel(
    const float* __restrict__ g, const ushort* __restrict__ W16,
    ushort* __restrict__ preb, int S) {
  const int lane = threadIdx.x;
  const int ct = blockIdx.x;            // 20 col-tiles over 320
  const int row0 = blockIdx.y * 16;
  int srow = row0 + (lane & 15); if (srow >= S) srow = S - 1;
  const float* gp = g + (size_t)srow * GI + 8 * (lane >> 4);
  const ushort* wp = W16 + ((size_t)ct * 24 * 64 + lane) * 8;

  f32x4 acc = {};
#pragma unroll 2
  for (int s = 0; s < 24; ++s) {
    const float4 a0 = *(const float4*)(gp + s * 32);
    const float4 a1 = *(const float4*)(gp + s * 32 + 4);
    const v8s bh = *(const v8s*)(wp + (size_t)s * 512);
    float xr[8] = {a0.x, a0.y, a0.z, a0.w, a1.x, a1.y, a1.z, a1.w};
    ushort hs[8], ls[8];
#pragma unroll
    for (int j = 0; j < 8; ++j) tsplit(xr[j], hs[j], ls[j]);
    const v8s ah = mk8(hs), al = mk8(ls);
    acc = MFMA16(ah, bh, acc);
    acc = MFMA16(al, bh, acc);
  }
  const int col = ct * 16 + (lane & 15);
#pragma unroll
  for (int r = 0; r < 4; ++r) {
    int sr = row0 + (lane >> 4) * 4 + r;
    if (sr < S) preb[(size_t)sr * 320 + col] = bf16rn(acc[r]);
  }
}

// ---------------- h1s: fused per-pair MLP, 16 pairs/wave, deep gather pipeline -
// phase1: h1 = relu((g_i.*g_j)@W1c + pre_i + pre_j + phi + b1) -> 5KB LDS
// phase2: score = relu(h1@W2 + b2) @ W3 + b3 -> sOut
// Gathers software-pipelined 12-deep (bf16) / 6-deep (f32): compile-time ring
// indices (full unroll), per-slot waits -> ~24 loads in flight per wave.
template<bool BF16G>
__global__ __launch_bounds__(64, 2) void h1s_kernel(
    const float* __restrict__ g, const ushort* __restrict__ gb,
    const ushort* __restrict__ preb, const float* __restrict__ phiW,
    const ushort* __restrict__ WC,
    const ushort* __restrict__ W2Chi, const ushort* __restrict__ W2Clo,
    const float* __restrict__ b1p, const float2* __restrict__ b2w3,
    const float* __restrict__ b3,
    const int* __restrict__ mI, const int* __restrict__ aI,
    const int* __restrict__ db, const int* __restrict__ ge,
    const int* __restrict__ sp,
    float* __restrict__ sOut, int P) {
  __shared__ ushort h1L[16 * 160];
  const int lane = threadIdx.x;
  const int lrow = lane & 15, kg = lane >> 4;
  const int p0 = blockIdx.x * 16;
  const int myp = p0 + lrow;
  const int iA = mI[myp], jA = aI[myp];
  const int rdL = db[myp], rgL = 10 + ge[myp], rsL = 18 + sp[myp];

  f32x4 acc[10];
  {
    f32x4 z = {};
#pragma unroll
    for (int c = 0; c < 10; ++c) acc[c] = z;
  }

  if constexpr (BF16G) {
    // bf16 gathers, 12-deep prefetch ring (24 loads in flight)
    const ushort* gbi = gb + (size_t)iA * GI + 8 * kg;
    const ushort* gbj = gb + (size_t)jA * GI + 8 * kg;
    v8s pi[12], pj[12];
#pragma unroll
    for (int sp2 = 0; sp2 < 12; ++sp2) {
      pi[sp2] = *(const v8s*)(gbi + sp2 * 32);
      pj[sp2] = *(const v8s*)(gbj + sp2 * 32);
    }
#pragma unroll
    for (int s = 0; s < 24; ++s) {
      const int sl = s % 12;             // compile-time under full unroll
      const v8s ai = pi[sl], aj = pj[sl];
      if (s < 12) {
        pi[sl] = *(const v8s*)(gbi + (s + 12) * 32);
        pj[sl] = *(const v8s*)(gbj + (s + 12) * 32);
      }
      ushort pr[8];
#pragma unroll
      for (int j = 0; j < 8; ++j)
        pr[j] = bf16rn(b2f((ushort)ai[j]) * b2f((ushort)aj[j]));
      const v8s ap = mk8(pr);
#pragma unroll
      for (int c = 0; c < 10; ++c) {
        const v8s w = *(const v8s*)(WC + ((size_t)(c * 24 + s) * 64 + lane) * 8);
        acc[c] = MFMA16(ap, w, acc[c]);
      }
    }
  } else {
    // f32 gathers + hi/lo split A, 6-deep prefetch ring (24 loads in flight)
    const float* gi = g + (size_t)iA * GI + 8 * kg;
    const float* gj = g + (size_t)jA * GI + 8 * kg;
    float4 pa0[6], pa1[6], pb0[6], pb1[6];
#pragma unroll
    for (int sp2 = 0; sp2 < 6; ++sp2) {
      pa0[sp2] = *(const float4*)(gi + sp2 * 32);
      pa1[sp2] = *(const float4*)(gi + sp2 * 32 + 4);
      pb0[sp2] = *(const float4*)(gj + sp2 * 32);
      pb1[sp2] = *(const float4*)(gj + sp2 * 32 + 4);
    }
#pragma unroll
    for (int s = 0; s < 24; ++s) {
      const int sl = s % 6;              // compile-time under full unroll
      const float4 a0 = pa0[sl], a1 = pa1[sl];
      const float4 b0 = pb0[sl], b1v = pb1[sl];
      if (s < 18) {
        pa0[sl] = *(const float4*)(gi + (s + 6) * 32);
        pa1[sl] = *(const float4*)(gi + (s + 6) * 32 + 4);
        pb0[sl] = *(const float4*)(gj + (s + 6) * 32);
        pb1[sl] = *(const float4*)(gj + (s + 6) * 32 + 4);
      }
      float xr[8] = {a0.x * b0.x, a0.y * b0.y, a0.z * b0.z, a0.w * b0.w,
                     a1.x * b1v.x, a1.y * b1v.y, a1.z * b1v.z, a1.w * b1v.w};
      ushort hs[8], ls[8];
#pragma unroll
      for (int j = 0; j < 8; ++j) tsplit(xr[j], hs[j], ls[j]);
      const v8s ah = mk8(hs), al = mk8(ls);
#pragma unroll
      for (int c = 0; c < 10; ++c) {
        const v8s w = *(const v8s*)(WC + ((size_t)(c * 24 + s) * 64 + lane) * 8);
        acc[c] = MFMA16(ah, w, acc[c]);
        acc[c] = MFMA16(al, w, acc[c]);
      }
    }
  }

  // ---- epilogue 1: + pre_i + pre_j + phi + b1, relu, bf16 -> LDS ----
#pragma unroll
  for (int r = 0; r < 4; ++r) {
    const int p = kg * 4 + r;
    const int pI = __shfl(iA, p);
    const int pJ = __shfl(jA, p);
    const int rd = __shfl(rdL, p), rg = __shfl(rgL, p), rs = __shfl(rsL, p);
    const ushort* prI = preb + (size_t)pI * 320;
    const ushort* prJ = preb + (size_t)pJ * 320 + 160;
#pragma unroll
    for (int c = 0; c < 10; ++c) {
      const int col = c * 16 + lrow;
      float v = acc[c][r] + b1p[col] + b2f(prI[col]) + b2f(prJ[col])
              + phiW[rd * HPAD + col] + phiW[rg * HPAD + col] + phiW[rs * HPAD + col];
      v = fmaxf(v, 0.f);
      h1L[p * 160 + col] = bf16rn(v);
    }
  }
  __syncthreads();   // single wave: near-free, orders LDS transpose

  // ---- phase 2: h2 = relu(h1 @ W2 + b2); score = h2 @ W3 + b3 ----
  f32x4 acc2[10];
  {
    f32x4 z = {};
#pragma unroll
    for (int ct = 0; ct < 10; ++ct) acc2[ct] = z;
  }
#pragma unroll
  for (int s = 0; s < 5; ++s) {
    const v8s a = *(const v8s*)(&h1L[lrow * 160 + s * 32 + 8 * kg]);
#pragma unroll
    for (int ct = 0; ct < 10; ++ct) {
      const size_t o = ((size_t)(ct * 5 + s) * 64 + lane) * 8;
      const v8s wh = *(const v8s*)(W2Chi + o);
      const v8s wl = *(const v8s*)(W2Clo + o);
      acc2[ct] = MFMA16(a, wh, acc2[ct]);
      acc2[ct] = MFMA16(a, wl, acc2[ct]);
    }
  }
  float part[4] = {0.f, 0.f, 0.f, 0.f};
#pragma unroll
  for (int ct = 0; ct < 10; ++ct) {
    const float2 bw = b2w3[ct * 16 + lrow];
#pragma unroll
    for (int r = 0; r < 4; ++r)
      part[r] += fmaxf(acc2[ct][r] + bw.x, 0.f) * bw.y;
  }
#pragma unroll
  for (int m = 1; m < 16; m <<= 1) {
#pragma unroll
    for (int r = 0; r < 4; ++r) part[r] += __shfl_xor(part[r], m, 16);
  }
  if (lrow == 0) {
    const float bb = b3[0];
#pragma unroll
    for (int r = 0; r < 4; ++r) sOut[p0 + kg * 4 + r] = part[r] + bb;
  }
}

// ---------------- mid: segment softmax -> weighted -> gated g update ----------
// j-gathers from bf16 copy gb; gate dot uses f32 g (coalesced).
__global__ void mid_kernel(const float* __restrict__ g, const ushort* __restrict__ gb,
                           const float* __restrict__ s1,
                           const int* __restrict__ segs, const int* __restrict__ aI,
                           const float* __restrict__ Wf, const float* __restrict__ bf,
                           float* __restrict__ g2) {
  const int m = blockIdx.x;
  const int t = threadIdx.x;  // 256
  const int st = segs[m], en = segs[m + 1], n = en - st;
  if (n == 0) {
    for (int d = t; d < GI; d += 256) g2[m * GI + d] = g[m * GI + d];
    return;
  }
  __shared__ float red[256];
  __shared__ float wred[4][GI];
  float mx = -INFINITY;
  for (int p = st + t; p < en; p += 256) mx = fmaxf(mx, s1[p]);
  red[t] = mx; __syncthreads();
  for (int s = 128; s > 0; s >>= 1) { if (t < s) red[t] = fmaxf(red[t], red[t + s]); __syncthreads(); }
  mx = red[0]; __syncthreads();
  const int dg = t & 63, pg = t >> 6;
  float wv[12];
#pragma unroll
  for (int u = 0; u < 12; ++u) wv[u] = 0.f;
  float esum = 0.f;
  for (int p = st + pg; p < en; p += 4) {
    const float e = expf(s1[p] - mx);
    esum += e;
    const ushort* gj = gb + (size_t)aI[p] * GI + dg;
#pragma unroll
    for (int u = 0; u < 12; ++u) wv[u] += e * b2f(gj[u * 64]);
  }
  red[t] = (dg == 0) ? esum : 0.f; __syncthreads();
  for (int s = 128; s > 0; s >>= 1) { if (t < s) red[t] += red[t + s]; __syncthreads(); }
  const float denom = red[0]; __syncthreads();
#pragma unroll
  for (int u = 0; u < 12; ++u) wred[pg][dg + u * 64] = wv[u];
  __syncthreads();
  float part = 0.f;
  float wfin[3];
#pragma unroll
  for (int u = 0; u < 3; ++u) {
    const int d = t + u * 256;
    float wsv = (wred[0][d] + wred[1][d] + wred[2][d] + wred[3][d]) / denom;
    wfin[u] = wsv;
    part += g[(size_t)m * GI + d] * Wf[d] + wsv * Wf[GI + d];
  }
  red[t] = part; __syncthreads();
  for (int s = 128; s > 0; s >>= 1) { if (t < s) red[t] += red[t + s]; __syncthreads(); }
  const float f = 1.f / (1.f + expf(-(red[0] + bf[0])));
#pragma unroll
  for (int u = 0; u < 3; ++u) {
    const int d = t + u * 256;
    g2[(size_t)m * GI + d] = f * (float)m + (1.f - f) * wfin[u];
  }
}

// ---------------- coref_scores[p] = ms[i] + ms[j] + s2[p] ---------------------
__global__ void coref_kernel(const float* __restrict__ ms, const float* __restrict__ s2,
                             const int* __restrict__ mI, const int* __restrict__ aI,
                             float* __restrict__ out, int P) {
  int p = blockIdx.x * 256 + threadIdx.x;
  if (p >= P) return;
  out[p] = ms[mI[p]] + ms[aI[p]] + s2[p];
}

// ---------------- final segment softmax with epsilon --------------------------
__global__ void final_kernel(const float* __restrict__ c, const int* __restrict__ segs,
                             float* __restrict__ pairP, float* __restrict__ epsP) {
  const int m = blockIdx.x;
  const int t = threadIdx.x;  // 256
  const int st = segs[m], en = segs[m + 1], n = en - st;
  __shared__ float red[256];
  float mx = -INFINITY;
  for (int p = st + t; p < en; p += 256) mx = fmaxf(mx, c[p]);
  red[t] = mx; __syncthreads();
  for (int s = 128; s > 0; s >>= 1) { if (t < s) red[t] = fmaxf(red[t], red[t + s]); __syncthreads(); }
  mx = red[0]; __syncthreads();
  const float m2 = (n > 0) ? fmaxf(mx, 0.f) : 0.f;
  float sm = 0.f;
  for (int p = st + t; p < en; p += 256) sm += expf(c[p] - m2);
  red[t] = sm; __syncthreads();
  for (int s = 128; s > 0; s >>= 1) { if (t < s) red[t] += red[t + s]; __syncthreads(); }
  const float denom = red[0] + expf(-m2);
  for (int p = st + t; p < en; p += 256) pairP[p] = expf(c[p] - m2) / denom;
  if (t == 0) epsP[m] = expf(-m2) / denom;
}

extern "C" void kernel_launch(void* const* d_in, const int* in_sizes, int n_in,
                              void* d_out, int out_size, void* d_ws, size_t ws_size,
                              hipStream_t stream) {
  const float* g_i  = (const float*)d_in[0];
  const float* ms   = (const float*)d_in[1];
  const int*   mI   = (const int*)d_in[2];
  const int*   aI   = (const int*)d_in[3];
  const int*   db   = (const int*)d_in[4];
  const int*   ge   = (const int*)d_in[5];
  const int*   sp   = (const int*)d_in[6];
  const float* de   = (const float*)d_in[7];
  const float* gemb = (const float*)d_in[8];
  const float* semb = (const float*)d_in[9];
  const float* W1   = (const float*)d_in[10];
  const float* b1   = (const float*)d_in[11];
  const float* W2   = (const float*)d_in[12];
  const float* b2   = (const float*)d_in[13];
  const float* W3   = (const float*)d_in[14];
  const float* b3   = (const float*)d_in[15];
  const float* Wf   = (const float*)d_in[16];
  const float* bf   = (const float*)d_in[17];

  const int S = in_sizes[0] / GI;
  const int P = in_sizes[2];
  float* out = (float*)d_out;                 // [coref P | pairP P | epsP S]

  char* ws = (char*)d_ws;
  size_t off = 0;
  auto take = [&](size_t bytes) -> char* {
    char* p = ws + off;
    off = (off + bytes + 15) & ~(size_t)15;
    return p;
  };
  int*    segs  = (int*)   take((size_t)(S + 1) * 4);
  float*  phiW  = (float*) take((size_t)21 * HPAD * 4);
  ushort* preb  = (ushort*)take((size_t)S * 320 * 2);
  float*  g2    = (float*) take((size_t)S * GI * 4);
  float*  s1    = (float*) take((size_t)P * 4);
  float*  s2    = (float*) take((size_t)P * 4);
  ushort* Gb    = (ushort*)take((size_t)S * GI * 2);
  ushort* WC    = (ushort*)take((size_t)NWC * 2);
  ushort* W16   = (ushort*)take((size_t)NW16 * 2);
  ushort* W2Chi = (ushort*)take((size_t)NW2C * 2);
  ushort* W2Clo = (ushort*)take((size_t)NW2C * 2);
  float*  b1p   = (float*) take((size_t)HPAD * 4);
  float2* b2w3  = (float2*)take((size_t)HPAD * 8);

  const int gridSeg = (S + 1 + 255) / 256;
  const int gridPhi = (21 * HPAD + 255) / 256;
  const int padTot  = NWC + NW16 + NW2C + 2 * HPAD;
  const int gridPad = (padTot + 255) / 256;
  const int n4      = S * GI / 4;
  const int gridGb  = (n4 + 255) / 256;
  const dim3 gridPre(20, (S + 15) / 16);
  const int gridH   = P / 16;          // 5000 single-wave blocks
  const int gridCor = (P + 255) / 256;

  seg_kernel<<<gridSeg, 256, 0, stream>>>(mI, segs, P, S);
  phi_kernel<<<gridPhi, 256, 0, stream>>>(de, gemb, semb, W1, phiW);
  pad2_kernel<<<gridPad, 256, 0, stream>>>(W1, W2, b1, b2, W3, WC, W16,
                                           W2Chi, W2Clo, b1p, b2w3);
  g2b_kernel<<<gridGb, 256, 0, stream>>>(g_i, Gb, n4);

  // iteration 1 (g = g_i; bf16 gathers)
  pre3_kernel<<<gridPre, 64, 0, stream>>>(g_i, W16, preb, S);
  h1s_kernel<true><<<gridH, 64, 0, stream>>>(g_i, Gb, preb, phiW, WC, W2Chi, W2Clo,
                                             b1p, b2w3, b3, mI, aI, db, ge, sp, s1, P);
  mid_kernel<<<S, 256, 0, stream>>>(g_i, Gb, s1, segs, aI, Wf, bf, g2);

  // iteration 2 (g = g2; f32 hi/lo gathers)
  pre3_kernel<<<gridPre, 64, 0, stream>>>(g2, W16, preb, S);
  h1s_kernel<false><<<gridH, 64, 0, stream>>>(g2, Gb, preb, phiW, WC, W2Chi, W2Clo,
                                              b1p, b2w3, b3, mI, aI, db, ge, sp, s2, P);

  // outputs
  coref_kernel<<<gridCor, 256, 0, stream>>>(ms, s2, mI, aI, out, P);
  final_kernel<<<S, 256, 0, stream>>>(out, segs, out + P, out + 2 * (size_t)P);
}